// Round 5
// baseline (228.031 us; speedup 1.0000x reference)
//
#include <hip/hip_runtime.h>
#include <math.h>

#pragma clang fp contract(off)

#define NRAYS 4096
#define NS 512
#define NEL (NRAYS * NS)          // 2097152
#define TOPK 4000u
#define CHUNK 64

// d_out layout (floats), concatenated in reference return order
#define OFF_W     ((size_t)0)
#define OFF_BG    ((size_t)2097152)
#define OFF_DEPTH ((size_t)2101248)
#define OFF_FULL  ((size_t)2105344)
#define OFF_INV   ((size_t)4202496)

// ws layout (uints)
#define ST_TBITS 4
#define ST_M     5
#define ST_TIEN  6
#define ST_CNT   7
#define ST_TK4   11
#define WS_TIE   (16 + 5120)
#define TIE_CAP  8192u
#define WS_CIDX  (16 + 5120 + 8192)   // uint2 region (8B aligned)

#define AGLD(p) __hip_atomic_load((p), __ATOMIC_RELAXED, __HIP_MEMORY_SCOPE_AGENT)
#define AGST(p, v) __hip_atomic_store((p), (v), __ATOMIC_RELAXED, __HIP_MEMORY_SCOPE_AGENT)
#define TICKET(p) __hip_atomic_fetch_add((p), 1u, __ATOMIC_RELAXED, __HIP_MEMORY_SCOPE_AGENT)

__device__ __forceinline__ float tri_sample(const float* __restrict__ vol, int R,
                                            float cx, float cy, float cz) {
  #pragma clang fp contract(off)
  float c0 = fminf(fmaxf(cx, -1.0f), 1.0f);
  float c1 = fminf(fmaxf(cy, -1.0f), 1.0f);
  float c2 = fminf(fmaxf(cz, -1.0f), 1.0f);
  float fR = (float)(R - 1);
  float x = (c0 + 1.0f) * 0.5f * fR;
  float y = (c1 + 1.0f) * 0.5f * fR;
  float z = (c2 + 1.0f) * 0.5f * fR;
  float xf = fminf(fmaxf(floorf(x), 0.0f), (float)(R - 2));
  float yf = fminf(fmaxf(floorf(y), 0.0f), (float)(R - 2));
  float zf = fminf(fmaxf(floorf(z), 0.0f), (float)(R - 2));
  int x0 = (int)xf, y0 = (int)yf, z0 = (int)zf;
  float xd = x - xf, yd = y - yf, zd = z - zf;
  const float* p = vol + ((size_t)z0 * R + (size_t)y0) * R + (size_t)x0;
  float c000 = p[0], c001 = p[1];
  float c010 = p[R], c011 = p[R + 1];
  const float* q = p + (size_t)R * R;
  float c100 = q[0], c101 = q[1];
  float c110 = q[R], c111 = q[R + 1];
  float omx = 1.0f - xd, omy = 1.0f - yd, omz = 1.0f - zd;
  float c00 = c000 * omx + c001 * xd;
  float c01 = c010 * omx + c011 * xd;
  float c10 = c100 * omx + c101 * xd;
  float c11 = c110 * omx + c111 * xd;
  float a0 = c00 * omy + c01 * yd;
  float a1 = c10 * omy + c11 * yd;
  return a0 * omz + a1 * zd;
}

// One wave (64 thr) per ray. Chunks of 64 samples; every lane redundantly runs
// the exact left-to-right cumprod chain from LDS float4 broadcasts (branchless),
// capturing its own prefix T. Termination checked at chunk end only:
// processed chunks are bit-exact; skipped chunks have ref-w <= T <= 1e-4 so all
// mask bits are exact, |depth err| <= 1.2e-3, |w/bg err| <= 1e-4 (thr 4.4e-2).
__global__ __launch_bounds__(64) void k_march(
    const float* __restrict__ ro, const float* __restrict__ rd,
    const float* __restrict__ dens, const float* __restrict__ prb,
    const float* __restrict__ alpv, float* __restrict__ out,
    unsigned* __restrict__ state, uint2* __restrict__ cidx, unsigned cap2) {
  #pragma clang fp contract(off)
  const float STEP = (float)(3.0 * 1.7320508075688772 / 512.0);
  const float DIST = (float)((3.0 * 1.7320508075688772 / 512.0) * 25.0);
  const float INVG = 2.0f / 3.0f;
  int r = blockIdx.x;
  int lane = threadIdx.x;
  __shared__ __align__(16) float s_alpha[CHUNK];

  float ox = ro[r * 3 + 0], oy = ro[r * 3 + 1], oz = ro[r * 3 + 2];
  float dx = rd[r * 3 + 0], dy = rd[r * 3 + 1], dz = rd[r * 3 + 2];
  float vx = (dx == 0.0f) ? 1e-6f : dx;
  float vy = (dy == 0.0f) ? 1e-6f : dy;
  float vz = (dz == 0.0f) ? 1e-6f : dz;
  float tmin;
  {
    float rax = (1.5f - ox) / vx, rbx = (-1.5f - ox) / vx;
    float ray = (1.5f - oy) / vy, rby = (-1.5f - oy) / vy;
    float raz = (1.5f - oz) / vz, rbz = (-1.5f - oz) / vz;
    float m0 = fminf(rax, rbx), m1 = fminf(ray, rby), m2 = fminf(raz, rbz);
    tmin = fmaxf(fmaxf(m0, m1), m2);
    tmin = fminf(fmaxf(tmin, 2.0f), 6.0f);
  }

  unsigned rb = (unsigned)r * NS;
  float T = 1.0f;        // wave-uniform running transmittance
  float dsum = 0.0f;
  int c = 0;
  for (; c < 8; ++c) {
    int s = c * CHUNK + lane;
    float ts = tmin + STEP * (float)s;
    float px = ox + dx * ts;
    float py = oy + dy * ts;
    float pz = oz + dz * ts;
    bool inb = !((-1.5f > px) || (px > 1.5f) || (-1.5f > py) || (py > 1.5f) ||
                 (-1.5f > pz) || (pz > 1.5f));
    float a = 0.0f;
    float nx = 0.0f, ny = 0.0f, nz = 0.0f;
    if (inb) {
      nx = (px + 1.5f) * INVG - 1.0f;
      ny = (py + 1.5f) * INVG - 1.0f;
      nz = (pz + 1.5f) * INVG - 1.0f;
      float al = tri_sample(alpv, 128, nx, ny, nz);
      float feat = tri_sample(dens, 256, nx, ny, nz);  // independent chains overlap
      if (al > 0.001f) {
        float xx = feat + (-10.0f);
        float sp = fmaxf(xx, 0.0f) + log1pf(expf(-fabsf(xx)));
        a = 1.0f - expf(-(sp * DIST));
      }
    }
    s_alpha[lane] = a;
    __syncthreads();   // 1-wave block: ~free, orders ds_write -> ds_read

    // branchless redundant chain: every lane computes all 64 steps exactly,
    // capturing T-before-own-sample. Dependent path = 64 fmul.
    float Tpre = T;
    const float4* a4 = (const float4*)s_alpha;
    #pragma unroll
    for (int j = 0; j < 16; ++j) {
      float4 v = a4[j];
      int i0 = 4 * j;
      if (lane == i0    ) Tpre = T;
      T = T * ((1.0f - v.x) + 1e-10f);
      if (lane == i0 + 1) Tpre = T;
      T = T * ((1.0f - v.y) + 1e-10f);
      if (lane == i0 + 2) Tpre = T;
      T = T * ((1.0f - v.z) + 1e-10f);
      if (lane == i0 + 3) Tpre = T;
      T = T * ((1.0f - v.w) + 1e-10f);
    }
    float w = a * Tpre;
    dsum += w * ts;
    float sc = 0.0f, app = 0.0f;
    if (w > 1e-4f) {
      app = 1.0f;
      float pv = tri_sample(prb, 256, nx, ny, nz);
      sc = w * pv;
    }
    out[OFF_W + rb + s] = w;
    out[OFF_FULL + rb + s] = sc;   // score stash (0.0 bits == final mask 0.0)
    out[OFF_INV + rb + s] = app;   // app stash (== final inv unless full)

    unsigned u = __float_as_uint(sc);
    unsigned long long act = __ballot(u != 0u);
    if (act) {
      int ldr = (int)(__ffsll((unsigned long long)act) - 1);
      unsigned cnt = (unsigned)__popcll(act);
      unsigned wbase = 0;
      if (lane == ldr) wbase = atomicAdd(&state[ST_CNT], cnt);
      wbase = (unsigned)__shfl((int)wbase, ldr);
      if (u) {
        unsigned pre = (unsigned)__popcll(act & ((1ull << lane) - 1ull));
        unsigned pos = wbase + pre;
        if (pos < cap2) cidx[pos] = make_uint2(u, rb + (unsigned)s);
      }
    }
    __syncthreads();   // protect s_alpha reuse next chunk
    if (T <= 1e-4f) { ++c; break; }   // wave-uniform
  }
  // zero-fill truncated tail (masks exact; |w| <= 1e-4), vectorized
  float4 z4 = make_float4(0.0f, 0.0f, 0.0f, 0.0f);
  for (int s2 = c * CHUNK + lane * 4; s2 < NS; s2 += 256) {
    *(float4*)&out[OFF_W + rb + s2] = z4;
    *(float4*)&out[OFF_FULL + rb + s2] = z4;
    *(float4*)&out[OFF_INV + rb + s2] = z4;
  }
  for (int off = 32; off > 0; off >>= 1) dsum += __shfl_down(dsum, off);
  if (lane == 0) {
    out[OFF_DEPTH + r] = dsum;
    out[OFF_BG + r] = T;
  }
}

// Single block, 1024 threads: 3-pass radix select (11/11/10 bits) over the
// compact candidate list. Only __syncthreads — no cross-block sync.
__global__ __launch_bounds__(1024) void k_select(const float* __restrict__ score,
    const uint2* __restrict__ cidx, unsigned* __restrict__ state, unsigned cap2) {
  __shared__ unsigned s[2048];
  __shared__ unsigned s_sel1, s_base1, s_sel2, s_base2, s_done;
  int t = threadIdx.x;
  unsigned nc = state[ST_CNT];
  bool ovf = nc > cap2;
  int n = ovf ? NEL : (int)nc;

  // ---- pass 1: bits 31..21 ----
  s[t] = 0u; s[t + 1024] = 0u;
  if (t == 0) s_done = 0u;
  __syncthreads();
  for (int i = t; i < n; i += 1024) {
    unsigned u = ovf ? __float_as_uint(score[i]) : cidx[i].x;
    if (u) atomicAdd(&s[u >> 21], 1u);
  }
  __syncthreads();
  for (int off = 1; off < 2048; off <<= 1) {
    unsigned a0 = (t + off < 2048) ? s[t + off] : 0u;
    unsigned a1 = (t + 1024 + off < 2048) ? s[t + 1024 + off] : 0u;
    __syncthreads();
    s[t] += a0;
    s[t + 1024] += a1;
    __syncthreads();
  }
  if (t == 0 && s[0] < TOPK) {   // all positives selected
    s_done = 1u;
    state[ST_TBITS] = 0u;
    state[ST_M] = 0u;
  }
  __syncthreads();
  if (s_done) return;
  for (int i = t; i < 2048; i += 1024) {
    unsigned hi = (i + 1 < 2048) ? s[i + 1] : 0u;
    if (s[i] >= TOPK && hi < TOPK) { s_sel1 = (unsigned)i; s_base1 = hi; }
  }
  __syncthreads();
  unsigned sel1 = s_sel1, base1 = s_base1;
  __syncthreads();

  // ---- pass 2: bits 20..10 ----
  s[t] = 0u; s[t + 1024] = 0u;
  __syncthreads();
  for (int i = t; i < n; i += 1024) {
    unsigned u = ovf ? __float_as_uint(score[i]) : cidx[i].x;
    if (u && (u >> 21) == sel1) atomicAdd(&s[(u >> 10) & 0x7FFu], 1u);
  }
  __syncthreads();
  for (int off = 1; off < 2048; off <<= 1) {
    unsigned a0 = (t + off < 2048) ? s[t + off] : 0u;
    unsigned a1 = (t + 1024 + off < 2048) ? s[t + 1024 + off] : 0u;
    __syncthreads();
    s[t] += a0;
    s[t + 1024] += a1;
    __syncthreads();
  }
  for (int i = t; i < 2048; i += 1024) {
    unsigned hi = (i + 1 < 2048) ? s[i + 1] : 0u;
    if (base1 + s[i] >= TOPK && base1 + hi < TOPK) {
      s_sel2 = (unsigned)i; s_base2 = base1 + hi;
    }
  }
  __syncthreads();
  unsigned sel2 = s_sel2, base2 = s_base2;
  __syncthreads();

  // ---- pass 3: bits 9..0 ----
  s[t] = 0u; s[t + 1024] = 0u;
  __syncthreads();
  unsigned sel12 = (sel1 << 11) | sel2;
  for (int i = t; i < n; i += 1024) {
    unsigned u = ovf ? __float_as_uint(score[i]) : cidx[i].x;
    if (u && (u >> 10) == sel12) atomicAdd(&s[u & 0x3FFu], 1u);
  }
  __syncthreads();
  for (int off = 1; off < 2048; off <<= 1) {
    unsigned a0 = (t + off < 2048) ? s[t + off] : 0u;
    unsigned a1 = (t + 1024 + off < 2048) ? s[t + 1024 + off] : 0u;
    __syncthreads();
    s[t] += a0;
    s[t + 1024] += a1;
    __syncthreads();
  }
  if (t < 1024) {
    unsigned hi = s[t + 1];   // bins >= 1024 are zero
    if (base2 + s[t] >= TOPK && base2 + hi < TOPK) {
      unsigned tb = (sel1 << 21) | (sel2 << 10) | (unsigned)t;
      state[ST_TBITS] = tb;
      state[ST_M] = TOPK - (base2 + hi);
    }
  }
}

__global__ __launch_bounds__(256) void k_apply(float* __restrict__ out,
    const uint2* __restrict__ cidx, unsigned* __restrict__ state,
    unsigned* __restrict__ tie, unsigned cap2) {
  unsigned tb = state[ST_TBITS];
  unsigned nc = state[ST_CNT];
  bool ovf = nc > cap2;
  int n = ovf ? NEL : (int)nc;
  int t = threadIdx.x;
  for (int i = blockIdx.x * 256 + t; i < n; i += gridDim.x * 256) {
    unsigned u, idx;
    if (ovf) { u = __float_as_uint(out[OFF_FULL + i]); idx = (unsigned)i; }
    else     { uint2 pr = cidx[i]; u = pr.x; idx = pr.y; }
    if (!u) continue;
    if (tb == 0u || u > tb) {
      out[OFF_FULL + idx] = 1.0f;
      out[OFF_INV + idx] = 0.0f;
    } else if (u == tb) {
      atomicExch(&out[OFF_FULL + idx], 0.0f);   // coherent: patch may overwrite
      unsigned p = atomicAdd(&state[ST_TIEN], 1u);
      if (p < TIE_CAP) atomicExch(&tie[p], idx);
    } else {
      out[OFF_FULL + idx] = 0.0f;
    }
  }
  __shared__ unsigned s_last;
  __syncthreads();   // drains vmcnt: this block's atomics performed
  if (t == 0) s_last = (TICKET(&state[ST_TK4]) == (unsigned)(gridDim.x - 1)) ? 1u : 0u;
  __syncthreads();
  if (!s_last) return;
  // tie patch: first m ties in flat-index order become full
  if (t == 0 && tb != 0u) {
    unsigned ntie = AGLD(&state[ST_TIEN]);
    if (ntie > TIE_CAP) ntie = TIE_CAP;
    unsigned m = state[ST_M];
    if (m > ntie) m = ntie;
    for (unsigned k = 0; k < m; k++) {
      unsigned bi = k, bv = AGLD(&tie[k]);
      for (unsigned j = k + 1; j < ntie; j++) {
        unsigned v = AGLD(&tie[j]);
        if (v < bv) { bv = v; bi = j; }
      }
      unsigned tk = AGLD(&tie[k]);
      AGST(&tie[bi], tk);
      AGST(&tie[k], bv);
      atomicExch(&out[OFF_FULL + bv], 1.0f);
      atomicExch(&out[OFF_INV + bv], 0.0f);
    }
  }
}

extern "C" void kernel_launch(void* const* d_in, const int* in_sizes, int n_in,
                              void* d_out, int out_size, void* d_ws, size_t ws_size,
                              hipStream_t stream) {
  const float* ro = (const float*)d_in[0];
  const float* rd = (const float*)d_in[1];
  const float* dens = (const float*)d_in[2];
  const float* prb = (const float*)d_in[3];
  const float* alpv = (const float*)d_in[4];
  float* out = (float*)d_out;
  unsigned* ws = (unsigned*)d_ws;
  long long cap_ll = ((long long)(ws_size / 4) - (long long)WS_CIDX) / 2;
  if (cap_ll < 0) cap_ll = 0;
  unsigned cap2 = (cap_ll > 0x7FFFFFFFLL) ? 0x7FFFFFFFu : (unsigned)cap_ll;
  uint2* cidx = (uint2*)(ws + WS_CIDX);

  hipMemsetAsync(ws, 0, 16 * sizeof(unsigned), stream);
  k_march<<<NRAYS, CHUNK, 0, stream>>>(ro, rd, dens, prb, alpv, out, ws, cidx, cap2);
  k_select<<<1, 1024, 0, stream>>>(out + OFF_FULL, cidx, ws, cap2);
  k_apply<<<64, 256, 0, stream>>>(out, cidx, ws, ws + WS_TIE, cap2);
}

// Round 6
// 118.476 us; speedup vs baseline: 1.9247x; 1.9247x over previous
//
#include <hip/hip_runtime.h>
#include <math.h>

#pragma clang fp contract(off)

#define NRAYS 4096
#define NS 512
#define NEL (NRAYS * NS)          // 2097152
#define TOPK 4000u
#define TOPK_NB 64

// d_out layout (floats), concatenated in reference return order
#define OFF_W     ((size_t)0)
#define OFF_BG    ((size_t)2097152)
#define OFF_DEPTH ((size_t)2101248)
#define OFF_FULL  ((size_t)2105344)
#define OFF_INV   ((size_t)4202496)

// ws layout (uints)
#define ST_TIEN  6
#define ST_CNT   7
#define ST_TK1   8
#define ST_TK2   9
#define ST_TK3   10
#define ST_TK4   11
#define WS_H1    16
#define WS_H2    (16 + 2048)
#define WS_H3    (16 + 4096)
#define WS_TIE   (16 + 5120)
#define TIE_CAP  8192u
#define WS_CIDX  (16 + 5120 + 8192)   // uint2 region (8B aligned)

#define AGLD(p) __hip_atomic_load((p), __ATOMIC_RELAXED, __HIP_MEMORY_SCOPE_AGENT)
#define AGST(p, v) __hip_atomic_store((p), (v), __ATOMIC_RELAXED, __HIP_MEMORY_SCOPE_AGENT)
#define TICKET(p) __hip_atomic_fetch_add((p), 1u, __ATOMIC_RELAXED, __HIP_MEMORY_SCOPE_AGENT)

struct Corners {
  float c000, c001, c010, c011, c100, c101, c110, c111;
  float xd, yd, zd;
};

__device__ __forceinline__ void tri_fetch(const float* __restrict__ vol, int R,
                                          float cx, float cy, float cz, Corners& f) {
  #pragma clang fp contract(off)
  float c0 = fminf(fmaxf(cx, -1.0f), 1.0f);
  float c1 = fminf(fmaxf(cy, -1.0f), 1.0f);
  float c2 = fminf(fmaxf(cz, -1.0f), 1.0f);
  float fR = (float)(R - 1);
  float x = (c0 + 1.0f) * 0.5f * fR;
  float y = (c1 + 1.0f) * 0.5f * fR;
  float z = (c2 + 1.0f) * 0.5f * fR;
  float xf = fminf(fmaxf(floorf(x), 0.0f), (float)(R - 2));
  float yf = fminf(fmaxf(floorf(y), 0.0f), (float)(R - 2));
  float zf = fminf(fmaxf(floorf(z), 0.0f), (float)(R - 2));
  int x0 = (int)xf, y0 = (int)yf, z0 = (int)zf;
  f.xd = x - xf; f.yd = y - yf; f.zd = z - zf;
  const float* p = vol + ((size_t)z0 * R + (size_t)y0) * R + (size_t)x0;
  f.c000 = p[0]; f.c001 = p[1];
  f.c010 = p[R]; f.c011 = p[R + 1];
  const float* q = p + (size_t)R * R;
  f.c100 = q[0]; f.c101 = q[1];
  f.c110 = q[R]; f.c111 = q[R + 1];
}

__device__ __forceinline__ float tri_lerp(const Corners& f) {
  #pragma clang fp contract(off)
  float omx = 1.0f - f.xd, omy = 1.0f - f.yd, omz = 1.0f - f.zd;
  float c00 = f.c000 * omx + f.c001 * f.xd;
  float c01 = f.c010 * omx + f.c011 * f.xd;
  float c10 = f.c100 * omx + f.c101 * f.xd;
  float c11 = f.c110 * omx + f.c111 * f.xd;
  float a0 = c00 * omy + c01 * f.yd;
  float a1 = c10 * omy + c11 * f.yd;
  return a0 * omz + a1 * f.zd;
}

// One wave per ray, 4 rays per 256-thr block, no block-level syncs.
// Chunks of 64 samples; next chunk's alpha/density corners prefetched under the
// current chunk's cumprod chain; prob corners fetched unconditionally (inb) so
// the post-chain path is lerp-only. Termination at chunk end when T<=1e-4:
// processed chunks bit-exact; skipped chunks have ref-w <= 1e-4 so mask bits
// exact, |depth err| <= ~1e-3, |w/bg err| <= 1e-4 (threshold 4.4e-2).
__global__ __launch_bounds__(256) void k_march(
    const float* __restrict__ ro, const float* __restrict__ rd,
    const float* __restrict__ dens, const float* __restrict__ prb,
    const float* __restrict__ alpv, float* __restrict__ out,
    unsigned* __restrict__ state, uint2* __restrict__ cidx, unsigned cap2) {
  #pragma clang fp contract(off)
  const float STEP = (float)(3.0 * 1.7320508075688772 / 512.0);
  const float DIST = (float)((3.0 * 1.7320508075688772 / 512.0) * 25.0);
  const float INVG = 2.0f / 3.0f;
  int wid = threadIdx.x >> 6;
  int lane = threadIdx.x & 63;
  int r = blockIdx.x * 4 + wid;
  __shared__ __align__(16) float s_alpha[4][64];
  float* sa = s_alpha[wid];

  float ox = ro[r * 3 + 0], oy = ro[r * 3 + 1], oz = ro[r * 3 + 2];
  float dx = rd[r * 3 + 0], dy = rd[r * 3 + 1], dz = rd[r * 3 + 2];
  float vx = (dx == 0.0f) ? 1e-6f : dx;
  float vy = (dy == 0.0f) ? 1e-6f : dy;
  float vz = (dz == 0.0f) ? 1e-6f : dz;
  float tmin;
  {
    float rax = (1.5f - ox) / vx, rbx = (-1.5f - ox) / vx;
    float ray = (1.5f - oy) / vy, rby = (-1.5f - oy) / vy;
    float raz = (1.5f - oz) / vz, rbz = (-1.5f - oz) / vz;
    float m0 = fminf(rax, rbx), m1 = fminf(ray, rby), m2 = fminf(raz, rbz);
    tmin = fmaxf(fmaxf(m0, m1), m2);
    tmin = fminf(fmaxf(tmin, 2.0f), 6.0f);
  }

  unsigned rb = (unsigned)r * NS;
  float T = 1.0f;
  float dsum = 0.0f;

  // prologue: fetch chunk 0 A/D corners
  float tsC, nxC, nyC, nzC; bool inbC;
  {
    int sS = lane;
    tsC = tmin + STEP * (float)sS;
    float px = ox + dx * tsC, py = oy + dy * tsC, pz = oz + dz * tsC;
    inbC = !((-1.5f > px) || (px > 1.5f) || (-1.5f > py) || (py > 1.5f) ||
             (-1.5f > pz) || (pz > 1.5f));
    nxC = (px + 1.5f) * INVG - 1.0f;
    nyC = (py + 1.5f) * INVG - 1.0f;
    nzC = (pz + 1.5f) * INVG - 1.0f;
  }
  Corners faC, fdC;
  if (inbC) { tri_fetch(alpv, 128, nxC, nyC, nzC, faC); tri_fetch(dens, 256, nxC, nyC, nzC, fdC); }

  int cdone = 8;
  #pragma unroll
  for (int c = 0; c < 8; ++c) {
    // consume current A/D (already fetched) -> frees their registers early
    float al = 0.0f, feat = 0.0f;
    if (inbC) { al = tri_lerp(faC); feat = tri_lerp(fdC); }
    // issue current prob corners (consumed after the chain)
    Corners fp;
    if (inbC) tri_fetch(prb, 256, nxC, nyC, nzC, fp);
    // issue next chunk's A/D corners (consumed next iteration)
    float tsN = 0.0f, nxN = 0.0f, nyN = 0.0f, nzN = 0.0f; bool inbN = false;
    Corners faN, fdN;
    if (c < 7) {
      int sS = (c + 1) * 64 + lane;
      tsN = tmin + STEP * (float)sS;
      float px = ox + dx * tsN, py = oy + dy * tsN, pz = oz + dz * tsN;
      inbN = !((-1.5f > px) || (px > 1.5f) || (-1.5f > py) || (py > 1.5f) ||
               (-1.5f > pz) || (pz > 1.5f));
      nxN = (px + 1.5f) * INVG - 1.0f;
      nyN = (py + 1.5f) * INVG - 1.0f;
      nzN = (pz + 1.5f) * INVG - 1.0f;
      if (inbN) { tri_fetch(alpv, 128, nxN, nyN, nzN, faN); tri_fetch(dens, 256, nxN, nyN, nzN, fdN); }
    }

    float a = 0.0f;
    if (inbC && al > 0.001f) {
      float xx = feat + (-10.0f);
      float sp = fmaxf(xx, 0.0f) + log1pf(expf(-fabsf(xx)));
      a = 1.0f - expf(-(sp * DIST));
    }

    // wave-local LDS exchange: waitcnt guards WAR (prior chunk's reads) and
    // RAW (this write complete before same-wave reads issue).
    asm volatile("s_waitcnt lgkmcnt(0)" ::: "memory");
    sa[lane] = a;
    asm volatile("s_waitcnt lgkmcnt(0)" ::: "memory");

    // branchless redundant exact left-to-right cumprod; lane captures its prefix
    float Tpre = T;
    const float4* a4 = (const float4*)sa;
    #pragma unroll
    for (int j = 0; j < 16; ++j) {
      float4 v = a4[j];
      int i0 = 4 * j;
      if (lane == i0    ) Tpre = T;
      T = T * ((1.0f - v.x) + 1e-10f);
      if (lane == i0 + 1) Tpre = T;
      T = T * ((1.0f - v.y) + 1e-10f);
      if (lane == i0 + 2) Tpre = T;
      T = T * ((1.0f - v.z) + 1e-10f);
      if (lane == i0 + 3) Tpre = T;
      T = T * ((1.0f - v.w) + 1e-10f);
    }
    float w = a * Tpre;
    dsum += w * tsC;
    float sc = 0.0f, app = 0.0f;
    if (w > 1e-4f) { app = 1.0f; sc = w * tri_lerp(fp); }
    int s = c * 64 + lane;
    out[OFF_W + rb + s] = w;
    out[OFF_FULL + rb + s] = sc;   // score stash (0.0 bits == final mask 0.0)
    out[OFF_INV + rb + s] = app;   // app stash (== final inv unless full)

    unsigned u = __float_as_uint(sc);
    unsigned long long act = __ballot(u != 0u);
    if (act) {
      int ldr = (int)(__ffsll((unsigned long long)act) - 1);
      unsigned cnt = (unsigned)__popcll(act);
      unsigned wbase = 0;
      if (lane == ldr) wbase = atomicAdd(&state[ST_CNT], cnt);
      wbase = (unsigned)__shfl((int)wbase, ldr);
      if (u) {
        unsigned pre = (unsigned)__popcll(act & ((1ull << lane) - 1ull));
        unsigned pos = wbase + pre;
        if (pos < cap2) cidx[pos] = make_uint2(u, rb + (unsigned)s);
      }
    }
    if (T <= 1e-4f) { cdone = c + 1; break; }   // wave-uniform
    tsC = tsN; inbC = inbN; nxC = nxN; nyC = nyN; nzC = nzN;
    faC = faN; fdC = fdN;
  }

  // zero-fill truncated tail (masks exact; |w| <= 1e-4), vectorized
  float4 z4 = make_float4(0.0f, 0.0f, 0.0f, 0.0f);
  for (int s2 = cdone * 64 + lane * 4; s2 < NS; s2 += 256) {
    *(float4*)&out[OFF_W + rb + s2] = z4;
    *(float4*)&out[OFF_FULL + rb + s2] = z4;
    *(float4*)&out[OFF_INV + rb + s2] = z4;
  }
  for (int off = 32; off > 0; off >>= 1) dsum += __shfl_down(dsum, off);
  if (lane == 0) {
    out[OFF_DEPTH + r] = dsum;
    out[OFF_BG + r] = T;
  }
}

// spin grid-barrier: valid because all TOPK_NB=64 blocks are co-resident.
// __syncthreads drains this block's vmem (atomics performed at coherent point)
// before the ticket; spinners see ctr==NB only after every block's atomics.
__device__ __forceinline__ void gbar(unsigned* ctr) {
  __syncthreads();
  if (threadIdx.x == 0) {
    TICKET(ctr);
    while (AGLD(ctr) < (unsigned)TOPK_NB) __builtin_amdgcn_s_sleep(8);
  }
  __syncthreads();
}

// suffix radix-find over nbins bins of global hist g. All blocks run this
// redundantly on identical data -> identical results. res[0]=sel bin,
// res[1]=count of elements strictly above sel bin (base included).
__device__ void find_in(const unsigned* __restrict__ g, int nbins, unsigned base,
                        unsigned* sb, unsigned* s_loc, unsigned* res, int t) {
  int C = nbins >> 8;
  for (int i = t; i < nbins; i += 256) sb[i] = AGLD(&g[i]);
  __syncthreads();
  unsigned csum = 0;
  int b0 = t * C;
  for (int k = 0; k < C; k++) csum += sb[b0 + k];
  s_loc[t] = csum;
  __syncthreads();
  for (int off = 1; off < 256; off <<= 1) {
    unsigned v = (t + off < 256) ? s_loc[t + off] : 0u;
    __syncthreads();
    s_loc[t] += v;
    __syncthreads();
  }
  unsigned run = (t + 1 < 256) ? s_loc[t + 1] : 0u;
  for (int k = C - 1; k >= 0; k--) {
    unsigned nxt = run;
    run += sb[b0 + k];
    if (base + run >= TOPK && base + nxt < TOPK) {
      res[0] = (unsigned)(b0 + k);
      res[1] = base + nxt;
    }
  }
  __syncthreads();
}

// 64 blocks x 256: hist1 -> bar -> find1 (redundant) -> hist2 -> bar -> find2
// -> hist3 -> bar -> find3 -> apply -> bar -> block0 tie patch.
__global__ __launch_bounds__(256) void k_topk(
    float* __restrict__ out, const uint2* __restrict__ cidx,
    unsigned* __restrict__ state, unsigned* __restrict__ h1,
    unsigned* __restrict__ h2, unsigned* __restrict__ h3,
    unsigned* __restrict__ tie, unsigned cap2) {
  __shared__ unsigned sh[2048];
  __shared__ unsigned s_loc[256];
  __shared__ unsigned res[2];
  int t = threadIdx.x;
  const float* score = out + OFF_FULL;
  unsigned nc = AGLD(&state[ST_CNT]);
  bool ovf = nc > cap2;
  int n = ovf ? NEL : (int)nc;

  // ---- pass 1: bits 31..21 ----
  for (int i = t; i < 2048; i += 256) sh[i] = 0u;
  __syncthreads();
  for (int i = blockIdx.x * 256 + t; i < n; i += TOPK_NB * 256) {
    unsigned u = ovf ? __float_as_uint(score[i]) : cidx[i].x;
    if (u) atomicAdd(&sh[u >> 21], 1u);
  }
  __syncthreads();
  for (int i = t; i < 2048; i += 256) { unsigned v = sh[i]; if (v) atomicAdd(&h1[i], v); }
  gbar(&state[ST_TK1]);
  find_in(h1, 2048, 0u, sh, s_loc, res, t);
  unsigned total = s_loc[0];
  bool done = (total < TOPK);
  unsigned tb = 0u, M = 0u;
  unsigned sel1 = res[0], base1 = res[1];
  __syncthreads();   // everyone has read res/s_loc before reuse

  if (!done) {
    // ---- pass 2: bits 20..10 ----
    for (int i = t; i < 2048; i += 256) sh[i] = 0u;
    __syncthreads();
    for (int i = blockIdx.x * 256 + t; i < n; i += TOPK_NB * 256) {
      unsigned u = ovf ? __float_as_uint(score[i]) : cidx[i].x;
      if (u && (u >> 21) == sel1) atomicAdd(&sh[(u >> 10) & 0x7FFu], 1u);
    }
    __syncthreads();
    for (int i = t; i < 2048; i += 256) { unsigned v = sh[i]; if (v) atomicAdd(&h2[i], v); }
    gbar(&state[ST_TK2]);
    find_in(h2, 2048, base1, sh, s_loc, res, t);
    unsigned sel2 = res[0], base2 = res[1];
    __syncthreads();

    // ---- pass 3: bits 9..0 ----
    for (int i = t; i < 1024; i += 256) sh[i] = 0u;
    __syncthreads();
    unsigned sel12 = (sel1 << 11) | sel2;
    for (int i = blockIdx.x * 256 + t; i < n; i += TOPK_NB * 256) {
      unsigned u = ovf ? __float_as_uint(score[i]) : cidx[i].x;
      if (u && (u >> 10) == sel12) atomicAdd(&sh[u & 0x3FFu], 1u);
    }
    __syncthreads();
    for (int i = t; i < 1024; i += 256) { unsigned v = sh[i]; if (v) atomicAdd(&h3[i], v); }
    gbar(&state[ST_TK3]);
    find_in(h3, 1024, base2, sh, s_loc, res, t);
    tb = (sel1 << 21) | (sel2 << 10) | res[0];
    M = TOPK - res[1];
  }

  // ---- apply ----
  for (int i = blockIdx.x * 256 + t; i < n; i += TOPK_NB * 256) {
    unsigned u, idx;
    if (ovf) { u = __float_as_uint(score[i]); idx = (unsigned)i; }
    else     { uint2 pr = cidx[i]; u = pr.x; idx = pr.y; }
    if (!u) continue;
    if (tb == 0u || u > tb) {
      out[OFF_FULL + idx] = 1.0f;
      out[OFF_INV + idx] = 0.0f;
    } else if (u == tb) {
      atomicExch(&out[OFF_FULL + idx], 0.0f);   // coherent: patch may overwrite
      unsigned p = atomicAdd(&state[ST_TIEN], 1u);
      if (p < TIE_CAP) atomicExch(&tie[p], idx);
    } else {
      out[OFF_FULL + idx] = 0.0f;
    }
  }
  gbar(&state[ST_TK4]);
  // tie patch: first M ties in flat-index order become full
  if (blockIdx.x == 0 && t == 0 && tb != 0u) {
    unsigned ntie = AGLD(&state[ST_TIEN]);
    if (ntie > TIE_CAP) ntie = TIE_CAP;
    unsigned m = M;
    if (m > ntie) m = ntie;
    for (unsigned k = 0; k < m; k++) {
      unsigned bi = k, bv = AGLD(&tie[k]);
      for (unsigned j = k + 1; j < ntie; j++) {
        unsigned v = AGLD(&tie[j]);
        if (v < bv) { bv = v; bi = j; }
      }
      unsigned tk = AGLD(&tie[k]);
      AGST(&tie[bi], tk);
      AGST(&tie[k], bv);
      atomicExch(&out[OFF_FULL + bv], 1.0f);
      atomicExch(&out[OFF_INV + bv], 0.0f);
    }
  }
}

extern "C" void kernel_launch(void* const* d_in, const int* in_sizes, int n_in,
                              void* d_out, int out_size, void* d_ws, size_t ws_size,
                              hipStream_t stream) {
  const float* ro = (const float*)d_in[0];
  const float* rd = (const float*)d_in[1];
  const float* dens = (const float*)d_in[2];
  const float* prb = (const float*)d_in[3];
  const float* alpv = (const float*)d_in[4];
  float* out = (float*)d_out;
  unsigned* ws = (unsigned*)d_ws;
  long long cap_ll = ((long long)(ws_size / 4) - (long long)WS_CIDX) / 2;
  if (cap_ll < 0) cap_ll = 0;
  unsigned cap2 = (cap_ll > 0x7FFFFFFFLL) ? 0x7FFFFFFFu : (unsigned)cap_ll;
  uint2* cidx = (uint2*)(ws + WS_CIDX);

  hipMemsetAsync(ws, 0, (16 + 5120) * sizeof(unsigned), stream);
  k_march<<<NRAYS / 4, 256, 0, stream>>>(ro, rd, dens, prb, alpv, out, ws, cidx, cap2);
  k_topk<<<TOPK_NB, 256, 0, stream>>>(out, cidx, ws, ws + WS_H1, ws + WS_H2,
                                      ws + WS_H3, ws + WS_TIE, cap2);
}